// Round 9
// baseline (256.080 us; speedup 1.0000x reference)
//
#include <hip/hip_runtime.h>
#include <cstdint>
#include <cstddef>

#define NT 256
#define LOG2E 1.4426950408889634f

typedef float v2f __attribute__((ext_vector_type(2)));
typedef float v4f __attribute__((ext_vector_type(4)));

#if defined(__has_builtin)
#  if __has_builtin(__builtin_amdgcn_exp2f)
#    define EXP2F(x) __builtin_amdgcn_exp2f(x)
#  else
#    define EXP2F(x) exp2f(x)
#  endif
#else
#  define EXP2F(x) exp2f(x)
#endif

// ---------------- shared-memory layout (float offsets) ----------------
enum {
  OFF_EEGB = 0,       // 8
  OFF_PSAW = 8,       // 16
  OFF_PSAB = 24,      // 8
  OFF_LOCW = 32,      // 24
  OFF_LOCB = 56,      // 8
  OFF_TGTW = 64,      // 8
  OFF_TGTB = 72,      // 8
  OFF_NG   = 80,      // 8
  OFF_NB   = 88,      // 8
  OFF_CINW = 96,      // 192 (q-rows pre-scaled by log2e)
  OFF_CINB = 288,     // 24
  OFF_COUTW= 312,     // 64
  OFF_COUTB= 376,     // 8
  OFF_SINW = 384,     // 192
  OFF_SINB = 576,     // 24
  OFF_SOUTW= 600,     // 64
  OFF_SOUTB= 664,     // 8
  OFF_OINW = 672,     // 192
  OFF_OINB = 864,     // 24
  OFF_OOUTW= 888,     // 64
  OFF_OOUTB= 952,     // 8
  OFF_FC1B = 960,     // 90 -> 1050
  OFF_PE30 = 1052,    // 8
  OFF_PE32 = 1060,    // 8 -> 1068
  OFF_Ebuf = 1068,    // 240
  OFF_Pbuf = 1308,    // 256
  OFF_Sbuf = 1564,    // 256
  OFF_Abuf = 1820,    // 256
  OFF_Lbuf = 2076,    // 256
  OFF_Tbuf = 2332,    // 256 (final q source; then final raw output for fc1)
  OFF_CAT  = 2588,    // 1008 -> 3596
  OFF_QP   = 3596,    // 32 groups x 20 = 640 -> 4236
  OFF_K8   = 4236,    // 8 sets x 8h x 36 = 2304 -> 6540
  OFF_V8   = 6540,    // 2304 -> 8844
  OFF_FCO  = 8844,    // 90 -> 8934
  SM_TOTAL = 8936,    // 35744 B -> 4 blocks/CU, 16 waves
  // aliases into K8/V8 region (time-disjoint):
  OFF_EEGW = OFF_K8,            // 672 floats [o][84], dead before phase A
  OFF_KF   = OFF_K8,            // final MHA K: 8h x 132 = 1056
  OFF_VF   = OFF_K8 + 1056,     // final MHA V: 1056
};

__device__ __forceinline__ float hsum4(v4f a) {
  v2f t = a.xy + a.zw;
  return t.x + t.y;
}

// 2-q-row softmax core: K/V read ONCE for both rows (no max pass: shift-invariant, bounded)
template<int LK>
__device__ __forceinline__ void attn2_core(float q1, float q2,
                                           const float* Kp, const float* Vp,
                                           float& ov1, float& ov2) {
  v4f la = {0.f,0.f,0.f,0.f}, Aa = la, lb = la, Ab = la;
  #pragma unroll
  for (int t = 0; t < (LK >> 2); t++) {
    v4f kk = *(const v4f*)(Kp + 4 * t);
    v4f vv = *(const v4f*)(Vp + 4 * t);
    v4f s1 = kk * q1, s2 = kk * q2;
    v4f e1 = { EXP2F(s1.x), EXP2F(s1.y), EXP2F(s1.z), EXP2F(s1.w) };
    v4f e2 = { EXP2F(s2.x), EXP2F(s2.y), EXP2F(s2.z), EXP2F(s2.w) };
    la += e1; Aa += e1 * vv;
    lb += e2; Ab += e2 * vv;
  }
  if constexpr ((LK & 3) != 0) {  // tail == 2 in all shapes used
    v2f kk = *(const v2f*)(Kp + (LK & ~3));
    v2f vv = *(const v2f*)(Vp + (LK & ~3));
    v2f s1 = kk * q1, s2 = kk * q2;
    v2f e1 = { EXP2F(s1.x), EXP2F(s1.y) };
    v2f e2 = { EXP2F(s2.x), EXP2F(s2.y) };
    la.xy = la.xy + e1; Aa.xy = Aa.xy + e1 * vv;
    lb.xy = lb.xy + e2; Ab.xy = Ab.xy + e2 * vv;
  }
  ov1 = hsum4(Aa) * __builtin_amdgcn_rcpf(hsum4(la));
  ov2 = hsum4(Ab) * __builtin_amdgcn_rcpf(hsum4(lb));
}

// full 2-row attention + out-proj (register weights) + LayerNorm via LDS exchange
template<int LK>
__device__ __forceinline__ void attn2_nv(float q1, float q2,
                                         const float* Kp, const float* Vp,
                                         float* qslot, int h,
                                         v4f woa, v4f wob, float bo, float gg, float bb,
                                         float& nv1, float& nv2) {
  float ov1, ov2;
  attn2_core<LK>(q1, q2, Kp, Vp, ov1, ov2);
  // intra-8-lane-group exchange (same wave -> program order, no barrier)
  qslot[h] = ov1; qslot[8 + h] = ov2;
  v4f c0 = *(const v4f*)qslot,       c1 = *(const v4f*)(qslot + 4);
  v4f d0 = *(const v4f*)(qslot + 8), d1 = *(const v4f*)(qslot + 12);
  float a1 = bo + hsum4(c0 * woa + c1 * wob);
  float a2 = bo + hsum4(d0 * woa + d1 * wob);
  // LN over the 8-group via a second exchange (replaces 6 ds_bpermute shuffles)
  qslot[h] = a1; qslot[8 + h] = a2;
  c0 = *(const v4f*)qslot;       c1 = *(const v4f*)(qslot + 4);
  d0 = *(const v4f*)(qslot + 8); d1 = *(const v4f*)(qslot + 12);
  float mu1 = hsum4(c0 + c1) * 0.125f;
  float mu2 = hsum4(d0 + d1) * 0.125f;
  v4f e0 = c0 - mu1, e1v = c1 - mu1;
  v4f f0 = d0 - mu2, f1v = d1 - mu2;
  float var1 = hsum4(e0 * e0 + e1v * e1v) * 0.125f;
  float var2 = hsum4(f0 * f0 + f1v * f1v) * 0.125f;
  nv1 = fmaf((a1 - mu1) * rsqrtf(var1 + 1e-5f), gg, bb);
  nv2 = fmaf((a2 - mu2) * rsqrtf(var2 + 1e-5f), gg, bb);
}

__global__ __launch_bounds__(NT, 4) void cmt_kernel(
    const float* __restrict__ eeg, const float* __restrict__ pupil,
    const float* __restrict__ speech, const float* __restrict__ action,
    const float* __restrict__ location, const float* __restrict__ tgt,
    const float* __restrict__ eeg_w, const float* __restrict__ eeg_b,
    const float* __restrict__ psa_w, const float* __restrict__ psa_b,
    const float* __restrict__ loc_w, const float* __restrict__ loc_b,
    const float* __restrict__ tgt_w, const float* __restrict__ tgt_b,
    const float* __restrict__ ng, const float* __restrict__ nb,
    const float* __restrict__ cin_w, const float* __restrict__ cin_b,
    const float* __restrict__ cout_w, const float* __restrict__ cout_b,
    const float* __restrict__ sin_w, const float* __restrict__ sin_b,
    const float* __restrict__ sout_w, const float* __restrict__ sout_b,
    const float* __restrict__ oin_w, const float* __restrict__ oin_b,
    const float* __restrict__ oout_w, const float* __restrict__ oout_b,
    const float* __restrict__ fc1_w, const float* __restrict__ fc1_b,
    float* __restrict__ out)
{
  __shared__ __align__(16) float sm[SM_TOTAL];
  const int tid = threadIdx.x;
  const int b = blockIdx.x;

#define CP(off, p, n) for (int i = tid; i < (n); i += NT) sm[(off)+i] = (p)[i]
#define CPQ(off, p, n, nq) for (int i = tid; i < (n); i += NT) sm[(off)+i] = (p)[i] * ((i < (nq)) ? LOG2E : 1.0f)

  // ---------- phase 0: stage weights ----------
  for (int i = tid; i < 640; i += NT) sm[OFF_EEGW + (i / 80) * 84 + (i % 80)] = eeg_w[i];
  CP(OFF_EEGB, eeg_b, 8);
  CP(OFF_PSAW, psa_w, 16);   CP(OFF_PSAB, psa_b, 8);
  CP(OFF_LOCW, loc_w, 24);   CP(OFF_LOCB, loc_b, 8);
  CP(OFF_TGTW, tgt_w, 8);    CP(OFF_TGTB, tgt_b, 8);
  CP(OFF_NG, ng, 8);         CP(OFF_NB, nb, 8);
  CPQ(OFF_CINW, cin_w, 192, 64);  CPQ(OFF_CINB, cin_b, 24, 8);
  CP(OFF_COUTW, cout_w, 64); CP(OFF_COUTB, cout_b, 8);
  CPQ(OFF_SINW, sin_w, 192, 64);  CPQ(OFF_SINB, sin_b, 24, 8);
  CP(OFF_SOUTW, sout_w, 64); CP(OFF_SOUTB, sout_b, 8);
  CPQ(OFF_OINW, oin_w, 192, 64);  CPQ(OFF_OINB, oin_b, 24, 8);
  CP(OFF_OOUTW, oout_w, 64); CP(OFF_OOUTB, oout_b, 8);
  CP(OFF_FC1B, fc1_b, 90);
  if (tid < 16) {
    const float divs[4] = {1.f, 0.1f, 0.01f, 0.001f};
    float pos = (tid < 8) ? 30.f : 32.f;
    int e = tid & 7;
    float x = pos * divs[e >> 1];
    float v = (e & 1) ? cosf(x) : sinf(x);
    sm[((tid < 8) ? OFF_PE30 : OFF_PE32) + e] = v;
  }
  __syncthreads();

  // ---------- phase 1: convs + positional encoding ----------
  if (tid < 240) {  // eeg conv2d -> e[30][8]
    int w = tid >> 3, o = tid & 7;
    const float* ep = eeg + (size_t)b * 4720 + 4 * w;
    const float* wr = sm + OFF_EEGW + o * 84;
    v4f acc4 = {0.f, 0.f, 0.f, 0.f};
    #pragma unroll
    for (int t = 0; t < 20; t++) {
      int ik0 = 2 * t, ik1 = 2 * t + 1;
      float2 x0 = *(const float2*)(ep + (ik0 / 20) * 2360 + (ik0 % 20) * 118);
      float2 x1 = *(const float2*)(ep + (ik1 / 20) * 2360 + (ik1 % 20) * 118);
      v4f xv = {x0.x, x0.y, x1.x, x1.y};
      acc4 += xv * *(const v4f*)(wr + 4 * t);
    }
    v2f s2 = acc4.xy + acc4.zw;
    sm[OFF_Ebuf + w * 8 + o] = s2.x + s2.y + sm[OFF_EEGB + o] + sm[OFF_PE30 + o];
  }
  {  // conv1d k=1 pad=1 -> length-32 sequences, + pe32
    int t = tid >> 3, o = tid & 7;
    bool inb = (t >= 1 && t <= 30);
    int ti = t - 1;
    float pe = sm[OFF_PE32 + o];
    float w0 = sm[OFF_PSAW + 2 * o], w1 = sm[OFF_PSAW + 2 * o + 1];
    float pb = sm[OFF_PSAB + o];
    float vp = pb, vs = pb, va = pb;
    float vl = sm[OFF_LOCB + o], vt = sm[OFF_TGTB + o];
    if (inb) {
      const float* pp = pupil    + (size_t)b * 60 + ti;
      const float* sp = speech   + (size_t)b * 60 + ti;
      const float* ap = action   + (size_t)b * 60 + ti;
      const float* lp = location + (size_t)b * 90 + ti;
      vp = fmaf(pp[0], w0, fmaf(pp[30], w1, vp));
      vs = fmaf(sp[0], w0, fmaf(sp[30], w1, vs));
      va = fmaf(ap[0], w0, fmaf(ap[30], w1, va));
      vl = fmaf(lp[0],  sm[OFF_LOCW + 3 * o],     vl);
      vl = fmaf(lp[30], sm[OFF_LOCW + 3 * o + 1], vl);
      vl = fmaf(lp[60], sm[OFF_LOCW + 3 * o + 2], vl);
      vt = fmaf(tgt[(size_t)b * 30 + ti], sm[OFF_TGTW + o], vt);
    }
    sm[OFF_Pbuf + tid] = vp + pe;
    sm[OFF_Sbuf + tid] = vs + pe;
    sm[OFF_Abuf + tid] = va + pe;
    sm[OFF_Lbuf + tid] = vl + pe;
    sm[OFF_Tbuf + tid] = vt + pe;
  }
  __syncthreads();

  const int g = tid >> 3, h = tid & 7;
  float* qslot = sm + OFF_QP + g * 20;

  // ---------- phase A: ALL 8 K/V sets, weights hoisted ----------
  {
    const int r = g;  // 0..31
    v4f cka = *(const v4f*)(sm + OFF_CINW + 64 + h * 8), ckb = *(const v4f*)(sm + OFF_CINW + 68 + h * 8);
    v4f cva = *(const v4f*)(sm + OFF_CINW + 128 + h * 8), cvb = *(const v4f*)(sm + OFF_CINW + 132 + h * 8);
    float cbk = sm[OFF_CINB + 8 + h], cbv = sm[OFF_CINB + 16 + h];
#define KV1(srcO, set, wka, wkb, wva, wvb, bk, bv) { \
    v4f xa = *(const v4f*)(sm + (srcO) + r * 8); \
    v4f xb = *(const v4f*)(sm + (srcO) + r * 8 + 4); \
    sm[OFF_K8 + (set) * 288 + h * 36 + r] = (bk) + hsum4(xa * (wka) + xb * (wkb)); \
    sm[OFF_V8 + (set) * 288 + h * 36 + r] = (bv) + hsum4(xa * (wva) + xb * (wvb)); }
    if (r < 30) KV1(OFF_Ebuf, 0, cka, ckb, cva, cvb, cbk, cbv);
    KV1(OFF_Pbuf, 1, cka, ckb, cva, cvb, cbk, cbv);
    KV1(OFF_Sbuf, 2, cka, ckb, cva, cvb, cbk, cbv);
    KV1(OFF_Abuf, 3, cka, ckb, cva, cvb, cbk, cbv);
    KV1(OFF_Lbuf, 4, cka, ckb, cva, cvb, cbk, cbv);
    v4f ska = *(const v4f*)(sm + OFF_SINW + 64 + h * 8), skb = *(const v4f*)(sm + OFF_SINW + 68 + h * 8);
    v4f sva = *(const v4f*)(sm + OFF_SINW + 128 + h * 8), svb = *(const v4f*)(sm + OFF_SINW + 132 + h * 8);
    float sbk = sm[OFF_SINB + 8 + h], sbv = sm[OFF_SINB + 16 + h];
    if (r < 30) KV1(OFF_Ebuf, 5, ska, skb, sva, svb, sbk, sbv);
    KV1(OFF_Pbuf, 6, ska, skb, sva, svb, sbk, sbv);
    KV1(OFF_Abuf, 7, ska, skb, sva, svb, sbk, sbv);
#undef KV1
  }
  __syncthreads();

  // ---------- phase B: 18 MHAs, 2 rows/thread, targets split across wave pairs ----------
#define KSET(s) (sm + OFF_K8 + (s) * 288 + h * 36)
#define VSET(s) (sm + OFF_V8 + (s) * 288 + h * 36)
  {
    v4f qwc_a = *(const v4f*)(sm + OFF_CINW + h * 8), qwc_b = *(const v4f*)(sm + OFF_CINW + h * 8 + 4);
    v4f woc_a = *(const v4f*)(sm + OFF_COUTW + h * 8), woc_b = *(const v4f*)(sm + OFF_COUTW + h * 8 + 4);
    float bqc = sm[OFF_CINB + h], boc = sm[OFF_COUTB + h];
    float gg = sm[OFF_NG + h], bb = sm[OFF_NB + h];
    float t1, t2;

    if (g < 16) {
      // ---- target e: rows g (0..15) and g+16 (16..29; clamped for g>=14) ----
      {
        const float* x1 = sm + OFF_Ebuf + g * 8;
        const float* x2 = sm + OFF_Ebuf + ((g < 14) ? (g + 16) : 13) * 8;
        v4f x1a = *(const v4f*)x1, x1b = *(const v4f*)(x1 + 4);
        v4f x2a = *(const v4f*)x2, x2b = *(const v4f*)(x2 + 4);
        float qc1 = bqc + hsum4(x1a * qwc_a + x1b * qwc_b);
        float qc2 = bqc + hsum4(x2a * qwc_a + x2b * qwc_b);
        float cat1, cat2;
        attn2_nv<32>(qc1, qc2, KSET(1), VSET(1), qslot, h, woc_a, woc_b, boc, gg, bb, cat1, cat2); // cross(e,p)
        attn2_nv<32>(qc1, qc2, KSET(3), VSET(3), qslot, h, woc_a, woc_b, boc, gg, bb, t1, t2);     // cross(e,a)
        cat1 += t1; cat2 += t2;
        attn2_nv<32>(qc1, qc2, KSET(4), VSET(4), qslot, h, woc_a, woc_b, boc, gg, bb, t1, t2);     // cross(e,l)
        cat1 += t1; cat2 += t2;
        {  // selfa(e)
          v4f qws_a = *(const v4f*)(sm + OFF_SINW + h * 8), qws_b = *(const v4f*)(sm + OFF_SINW + h * 8 + 4);
          v4f wos_a = *(const v4f*)(sm + OFF_SOUTW + h * 8), wos_b = *(const v4f*)(sm + OFF_SOUTW + h * 8 + 4);
          float qs1 = sm[OFF_SINB + h] + hsum4(x1a * qws_a + x1b * qws_b);
          float qs2 = sm[OFF_SINB + h] + hsum4(x2a * qws_a + x2b * qws_b);
          attn2_nv<30>(qs1, qs2, KSET(5), VSET(5), qslot, h, wos_a, wos_b, sm[OFF_SOUTB + h], gg, bb, t1, t2);
          cat1 += t1; cat2 += t2;
        }
        attn2_nv<32>(qc1, qc2, KSET(2), VSET(2), qslot, h, woc_a, woc_b, boc, gg, bb, t1, t2);     // cross(e,s)
        cat1 += t1; cat2 += t2;
        sm[OFF_CAT + g * 8 + h] = cat1;
        if (g < 14) sm[OFF_CAT + (g + 16) * 8 + h] = cat2;
      }
      // ---- target p: rows g and g+16 ----
      {
        const float* x1 = sm + OFF_Pbuf + g * 8;
        const float* x2 = sm + OFF_Pbuf + (g + 16) * 8;
        v4f x1a = *(const v4f*)x1, x1b = *(const v4f*)(x1 + 4);
        v4f x2a = *(const v4f*)x2, x2b = *(const v4f*)(x2 + 4);
        float qc1 = bqc + hsum4(x1a * qwc_a + x1b * qwc_b);
        float qc2 = bqc + hsum4(x2a * qwc_a + x2b * qwc_b);
        float cat1, cat2;
        attn2_nv<30>(qc1, qc2, KSET(0), VSET(0), qslot, h, woc_a, woc_b, boc, gg, bb, cat1, cat2); // cross(p,e)
        attn2_nv<32>(qc1, qc2, KSET(3), VSET(3), qslot, h, woc_a, woc_b, boc, gg, bb, t1, t2);     // cross(p,a)
        cat1 += t1; cat2 += t2;
        attn2_nv<32>(qc1, qc2, KSET(4), VSET(4), qslot, h, woc_a, woc_b, boc, gg, bb, t1, t2);     // cross(p,l)
        cat1 += t1; cat2 += t2;
        {  // selfa(p)
          v4f qws_a = *(const v4f*)(sm + OFF_SINW + h * 8), qws_b = *(const v4f*)(sm + OFF_SINW + h * 8 + 4);
          v4f wos_a = *(const v4f*)(sm + OFF_SOUTW + h * 8), wos_b = *(const v4f*)(sm + OFF_SOUTW + h * 8 + 4);
          float qs1 = sm[OFF_SINB + h] + hsum4(x1a * qws_a + x1b * qws_b);
          float qs2 = sm[OFF_SINB + h] + hsum4(x2a * qws_a + x2b * qws_b);
          attn2_nv<32>(qs1, qs2, KSET(6), VSET(6), qslot, h, wos_a, wos_b, sm[OFF_SOUTB + h], gg, bb, t1, t2);
          cat1 += t1; cat2 += t2;
        }
        attn2_nv<32>(qc1, qc2, KSET(2), VSET(2), qslot, h, woc_a, woc_b, boc, gg, bb, t1, t2);     // cross(p,s)
        cat1 += t1; cat2 += t2;
        sm[OFF_CAT + (30 + g) * 8 + h] = cat1;
        sm[OFF_CAT + (30 + g + 16) * 8 + h] = cat2;
      }
    } else {
      const int gq = g - 16;
      float car1, car2;
      // ---- target s: rows gq and gq+16 ----
      {
        const float* x1 = sm + OFF_Sbuf + gq * 8;
        const float* x2 = sm + OFF_Sbuf + (gq + 16) * 8;
        v4f x1a = *(const v4f*)x1, x1b = *(const v4f*)(x1 + 4);
        v4f x2a = *(const v4f*)x2, x2b = *(const v4f*)(x2 + 4);
        float qc1 = bqc + hsum4(x1a * qwc_a + x1b * qwc_b);
        float qc2 = bqc + hsum4(x2a * qwc_a + x2b * qwc_b);
        float cat1, cat2;
        attn2_nv<30>(qc1, qc2, KSET(0), VSET(0), qslot, h, woc_a, woc_b, boc, gg, bb, cat1, cat2); // cross(s,e)
        attn2_nv<32>(qc1, qc2, KSET(1), VSET(1), qslot, h, woc_a, woc_b, boc, gg, bb, t1, t2);     // cross(s,p)
        cat1 += t1; cat2 += t2;
        attn2_nv<32>(qc1, qc2, KSET(3), VSET(3), qslot, h, woc_a, woc_b, boc, gg, bb, t1, t2);     // cross(s,a)
        cat1 += t1; cat2 += t2;
        attn2_nv<32>(qc1, qc2, KSET(4), VSET(4), qslot, h, woc_a, woc_b, boc, gg, bb, car1, car2); // cross(s,l)
        sm[OFF_CAT + (94 + gq) * 8 + h] = cat1 + car1;
        sm[OFF_CAT + (94 + gq + 16) * 8 + h] = cat2 + car2;
      }
      // ---- target a: rows gq and gq+16 (reuses carry = nrm(cross(s,l)), original bug) ----
      {
        const float* x1 = sm + OFF_Abuf + gq * 8;
        const float* x2 = sm + OFF_Abuf + (gq + 16) * 8;
        v4f x1a = *(const v4f*)x1, x1b = *(const v4f*)(x1 + 4);
        v4f x2a = *(const v4f*)x2, x2b = *(const v4f*)(x2 + 4);
        float qc1 = bqc + hsum4(x1a * qwc_a + x1b * qwc_b);
        float qc2 = bqc + hsum4(x2a * qwc_a + x2b * qwc_b);
        float cat1, cat2;
        attn2_nv<30>(qc1, qc2, KSET(0), VSET(0), qslot, h, woc_a, woc_b, boc, gg, bb, cat1, cat2); // cross(a,e)
        attn2_nv<32>(qc1, qc2, KSET(1), VSET(1), qslot, h, woc_a, woc_b, boc, gg, bb, t1, t2);     // cross(a,p)
        cat1 += t1 + car1; cat2 += t2 + car2;
        {  // selfa(a)
          v4f qws_a = *(const v4f*)(sm + OFF_SINW + h * 8), qws_b = *(const v4f*)(sm + OFF_SINW + h * 8 + 4);
          v4f wos_a = *(const v4f*)(sm + OFF_SOUTW + h * 8), wos_b = *(const v4f*)(sm + OFF_SOUTW + h * 8 + 4);
          float qs1 = sm[OFF_SINB + h] + hsum4(x1a * qws_a + x1b * qws_b);
          float qs2 = sm[OFF_SINB + h] + hsum4(x2a * qws_a + x2b * qws_b);
          attn2_nv<32>(qs1, qs2, KSET(7), VSET(7), qslot, h, wos_a, wos_b, sm[OFF_SOUTB + h], gg, bb, t1, t2);
          cat1 += t1; cat2 += t2;
        }
        attn2_nv<32>(qc1, qc2, KSET(2), VSET(2), qslot, h, woc_a, woc_b, boc, gg, bb, t1, t2);     // cross(a,s)
        cat1 += t1; cat2 += t2;
        sm[OFF_CAT + (62 + gq) * 8 + h] = cat1;
        sm[OFF_CAT + (62 + gq + 16) * 8 + h] = cat2;
      }
    }
  }
#undef KSET
#undef VSET
  __syncthreads();

  // ---------- final MHA kv-proj of CAT (126 rows), weights hoisted ----------
  {
    v4f fka = *(const v4f*)(sm + OFF_OINW + 64 + h * 8), fkb = *(const v4f*)(sm + OFF_OINW + 68 + h * 8);
    v4f fva = *(const v4f*)(sm + OFF_OINW + 128 + h * 8), fvb = *(const v4f*)(sm + OFF_OINW + 132 + h * 8);
    float fbk = sm[OFF_OINB + 8 + h], fbv = sm[OFF_OINB + 16 + h];
    for (int r = g; r < 126; r += 32) {
      v4f xa = *(const v4f*)(sm + OFF_CAT + r * 8);
      v4f xb = *(const v4f*)(sm + OFF_CAT + r * 8 + 4);
      sm[OFF_KF + h * 132 + r] = fbk + hsum4(xa * fka + xb * fkb);
      sm[OFF_VF + h * 132 + r] = fbv + hsum4(xa * fva + xb * fvb);
    }
  }
  __syncthreads();

  // ---------- final attention (Lk=126, 2 rows/thread, waves 2-3) ----------
  if (g >= 16) {
    const int gq = g - 16;
    const float* x1 = sm + OFF_Tbuf + gq * 8;
    const float* x2 = sm + OFF_Tbuf + (gq + 16) * 8;
    v4f qwf_a = *(const v4f*)(sm + OFF_OINW + h * 8), qwf_b = *(const v4f*)(sm + OFF_OINW + h * 8 + 4);
    v4f x1a = *(const v4f*)x1, x1b = *(const v4f*)(x1 + 4);
    v4f x2a = *(const v4f*)x2, x2b = *(const v4f*)(x2 + 4);
    float qf1 = sm[OFF_OINB + h] + hsum4(x1a * qwf_a + x1b * qwf_b);
    float qf2 = sm[OFF_OINB + h] + hsum4(x2a * qwf_a + x2b * qwf_b);
    float ov1, ov2;
    attn2_core<126>(qf1, qf2, sm + OFF_KF + h * 132, sm + OFF_VF + h * 132, ov1, ov2);
    qslot[h] = ov1; qslot[8 + h] = ov2;
    v4f c0 = *(const v4f*)qslot,       c1 = *(const v4f*)(qslot + 4);
    v4f d0 = *(const v4f*)(qslot + 8), d1 = *(const v4f*)(qslot + 12);
    v4f wfo_a = *(const v4f*)(sm + OFF_OOUTW + h * 8), wfo_b = *(const v4f*)(sm + OFF_OOUTW + h * 8 + 4);
    float bfo = sm[OFF_OOUTB + h];
    sm[OFF_Tbuf + gq * 8 + h]        = bfo + hsum4(c0 * wfo_a + c1 * wfo_b);
    sm[OFF_Tbuf + (gq + 16) * 8 + h] = bfo + hsum4(d0 * wfo_a + d1 * wfo_b);
  }
  __syncthreads();

  // ---------- fc1 (2 threads per output) + channel softmax ----------
  if (tid < 180) {
    int j = tid >> 1, p = tid & 1;
    const v4f* w4 = (const v4f*)(fc1_w + j * 256);
    const v4f* o4 = (const v4f*)(sm + OFF_Tbuf);
    v4f acc4 = {0.f, 0.f, 0.f, 0.f};
    #pragma unroll 8
    for (int c = p; c < 64; c += 2) acc4 += o4[c] * w4[c];
    float acc = hsum4(acc4);
    acc += __shfl_xor(acc, 1);
    if (p == 0) sm[OFF_FCO + j] = acc + sm[OFF_FC1B + j];
  }
  __syncthreads();
  if (tid < 30) {
    float x0 = sm[OFF_FCO + 3 * tid], x1 = sm[OFF_FCO + 3 * tid + 1], x2 = sm[OFF_FCO + 3 * tid + 2];
    float m = fmaxf(x0, fmaxf(x1, x2));
    float e0 = __expf(x0 - m), e1 = __expf(x1 - m), e2 = __expf(x2 - m);
    float inv = __builtin_amdgcn_rcpf(e0 + e1 + e2);
    float* op = out + (size_t)b * 90;
    op[tid]      = e0 * inv;
    op[30 + tid] = e1 * inv;
    op[60 + tid] = e2 * inv;
  }
#undef CP
#undef CPQ
}

extern "C" void kernel_launch(void* const* d_in, const int* in_sizes, int n_in,
                              void* d_out, int out_size, void* d_ws, size_t ws_size,
                              hipStream_t stream) {
  (void)n_in; (void)out_size; (void)d_ws; (void)ws_size;
  int B = in_sizes[0] / 4720;  // eeg = (B,2,20,118)
  cmt_kernel<<<B, NT, 0, stream>>>(
      (const float*)d_in[0],  (const float*)d_in[1],  (const float*)d_in[2],
      (const float*)d_in[3],  (const float*)d_in[4],  (const float*)d_in[5],
      (const float*)d_in[6],  (const float*)d_in[7],  (const float*)d_in[8],
      (const float*)d_in[9],  (const float*)d_in[10], (const float*)d_in[11],
      (const float*)d_in[12], (const float*)d_in[13], (const float*)d_in[14],
      (const float*)d_in[15], (const float*)d_in[16], (const float*)d_in[17],
      (const float*)d_in[18], (const float*)d_in[19], (const float*)d_in[20],
      (const float*)d_in[21], (const float*)d_in[22], (const float*)d_in[23],
      (const float*)d_in[24], (const float*)d_in[25], (const float*)d_in[26],
      (const float*)d_in[27], (const float*)d_in[28], (const float*)d_in[29],
      (float*)d_out);
}

// Round 10
// 254.594 us; speedup vs baseline: 1.0058x; 1.0058x over previous
//
#include <hip/hip_runtime.h>
#include <cstdint>
#include <cstddef>

#define NT 256
#define LOG2E 1.4426950408889634f

typedef float v2f __attribute__((ext_vector_type(2)));
typedef float v4f __attribute__((ext_vector_type(4)));

#if defined(__has_builtin)
#  if __has_builtin(__builtin_amdgcn_exp2f)
#    define EXP2F(x) __builtin_amdgcn_exp2f(x)
#  else
#    define EXP2F(x) exp2f(x)
#  endif
#else
#  define EXP2F(x) exp2f(x)
#endif

// ---------------- shared-memory layout (float offsets) ----------------
enum {
  OFF_EEGB = 0,       // 8
  OFF_PSAW = 8,       // 16
  OFF_PSAB = 24,      // 8
  OFF_LOCW = 32,      // 24
  OFF_LOCB = 56,      // 8
  OFF_TGTW = 64,      // 8
  OFF_TGTB = 72,      // 8
  OFF_NG   = 80,      // 8
  OFF_NB   = 88,      // 8
  OFF_CINW = 96,      // 192 (q-rows pre-scaled by log2e)
  OFF_CINB = 288,     // 24
  OFF_COUTW= 312,     // 64
  OFF_COUTB= 376,     // 8
  OFF_SINW = 384,     // 192
  OFF_SINB = 576,     // 24
  OFF_SOUTW= 600,     // 64
  OFF_SOUTB= 664,     // 8
  OFF_OINW = 672,     // 192
  OFF_OINB = 864,     // 24
  OFF_OOUTW= 888,     // 64
  OFF_OOUTB= 952,     // 8
  OFF_FC1B = 960,     // 90 -> 1050
  OFF_PE30 = 1052,    // 8
  OFF_PE32 = 1060,    // 8 -> 1068
  OFF_Ebuf = 1068,    // 240
  OFF_Pbuf = 1308,    // 256
  OFF_Sbuf = 1564,    // 256
  OFF_Abuf = 1820,    // 256
  OFF_Lbuf = 2076,    // 256
  OFF_Tbuf = 2332,    // 256 (final q source; then final raw output for fc1)
  OFF_CAT  = 2588,    // 1008 -> 3596
  OFF_QP   = 3596,    // 32 groups x 20 = 640 -> 4236
  OFF_K8   = 4236,    // 8 sets x 8h x 36 = 2304 -> 6540
  OFF_V8   = 6540,    // 2304 -> 8844
  OFF_FCO  = 8844,    // 90 -> 8934
  SM_TOTAL = 8936,    // 35744 B -> 4 blocks/CU, 16 waves
  // aliases into K8/V8 region (time-disjoint):
  OFF_EEGW = OFF_K8,            // 672 floats [o][84], dead before phase A
  OFF_KF   = OFF_K8,            // final MHA K: 8h x 132 = 1056
  OFF_VF   = OFF_K8 + 1056,     // final MHA V: 1056
};

__device__ __forceinline__ float hsum4(v4f a) {
  v2f t = a.xy + a.zw;
  return t.x + t.y;
}

__device__ __forceinline__ float dot8(const float* __restrict__ x,
                                      const float* __restrict__ w, float bias) {
  v4f xa = *(const v4f*)x, xb = *(const v4f*)(x + 4);
  return bias + hsum4(xa * *(const v4f*)w + xb * *(const v4f*)(w + 4));
}

// 2-q-row softmax core: K/V read ONCE for both rows (no max pass: shift-invariant, bounded)
template<int LK>
__device__ __forceinline__ void attn2_core(float q1, float q2,
                                           const float* Kp, const float* Vp,
                                           float& ov1, float& ov2) {
  v4f la = {0.f,0.f,0.f,0.f}, Aa = la, lb = la, Ab = la;
  #pragma unroll
  for (int t = 0; t < (LK >> 2); t++) {
    v4f kk = *(const v4f*)(Kp + 4 * t);
    v4f vv = *(const v4f*)(Vp + 4 * t);
    v4f s1 = kk * q1, s2 = kk * q2;
    v4f e1 = { EXP2F(s1.x), EXP2F(s1.y), EXP2F(s1.z), EXP2F(s1.w) };
    v4f e2 = { EXP2F(s2.x), EXP2F(s2.y), EXP2F(s2.z), EXP2F(s2.w) };
    la += e1; Aa += e1 * vv;
    lb += e2; Ab += e2 * vv;
  }
  if constexpr ((LK & 3) != 0) {  // tail == 2 in all shapes used
    v2f kk = *(const v2f*)(Kp + (LK & ~3));
    v2f vv = *(const v2f*)(Vp + (LK & ~3));
    v2f s1 = kk * q1, s2 = kk * q2;
    v2f e1 = { EXP2F(s1.x), EXP2F(s1.y) };
    v2f e2 = { EXP2F(s2.x), EXP2F(s2.y) };
    la.xy = la.xy + e1; Aa.xy = Aa.xy + e1 * vv;
    lb.xy = lb.xy + e2; Ab.xy = Ab.xy + e2 * vv;
  }
  ov1 = hsum4(Aa) * __builtin_amdgcn_rcpf(hsum4(la));
  ov2 = hsum4(Ab) * __builtin_amdgcn_rcpf(hsum4(lb));
}

// 2-row attention + out-proj + LayerNorm. Weights read FROM LDS per call
// (no persistent register hoists -> no spill); rows finalized sequentially.
template<int LK>
__device__ __forceinline__ void attn2_nv(float q1, float q2,
                                         const float* Kp, const float* Vp,
                                         float* qslot, int h,
                                         const float* sm, int woutO, int boutO,
                                         float gg, float bb,
                                         float& nv1, float& nv2) {
  float ov1, ov2;
  attn2_core<LK>(q1, q2, Kp, Vp, ov1, ov2);
  // intra-8-lane-group exchange (same wave -> program order, no barrier)
  qslot[h] = ov1; qslot[8 + h] = ov2;
  v4f woa = *(const v4f*)(sm + woutO + h * 8);
  v4f wob = *(const v4f*)(sm + woutO + h * 8 + 4);
  float bo = sm[boutO + h];
  float a1, a2;
  {
    v4f c0 = *(const v4f*)qslot, c1 = *(const v4f*)(qslot + 4);
    a1 = bo + hsum4(c0 * woa + c1 * wob);
    v4f d0 = *(const v4f*)(qslot + 8), d1 = *(const v4f*)(qslot + 12);
    a2 = bo + hsum4(d0 * woa + d1 * wob);
  }
  // LN row 1 via exchange (3 LDS ops, replaces 6 bpermute shuffles)
  {
    qslot[h] = a1;
    v4f c0 = *(const v4f*)qslot, c1 = *(const v4f*)(qslot + 4);
    float mu = hsum4(c0 + c1) * 0.125f;
    v4f e0 = c0 - mu, e1 = c1 - mu;
    float var = hsum4(e0 * e0 + e1 * e1) * 0.125f;
    nv1 = fmaf((a1 - mu) * rsqrtf(var + 1e-5f), gg, bb);
  }
  // LN row 2
  {
    qslot[8 + h] = a2;
    v4f d0 = *(const v4f*)(qslot + 8), d1 = *(const v4f*)(qslot + 12);
    float mu = hsum4(d0 + d1) * 0.125f;
    v4f f0 = d0 - mu, f1 = d1 - mu;
    float var = hsum4(f0 * f0 + f1 * f1) * 0.125f;
    nv2 = fmaf((a2 - mu) * rsqrtf(var + 1e-5f), gg, bb);
  }
}

__global__ __launch_bounds__(NT, 4) void cmt_kernel(
    const float* __restrict__ eeg, const float* __restrict__ pupil,
    const float* __restrict__ speech, const float* __restrict__ action,
    const float* __restrict__ location, const float* __restrict__ tgt,
    const float* __restrict__ eeg_w, const float* __restrict__ eeg_b,
    const float* __restrict__ psa_w, const float* __restrict__ psa_b,
    const float* __restrict__ loc_w, const float* __restrict__ loc_b,
    const float* __restrict__ tgt_w, const float* __restrict__ tgt_b,
    const float* __restrict__ ng, const float* __restrict__ nb,
    const float* __restrict__ cin_w, const float* __restrict__ cin_b,
    const float* __restrict__ cout_w, const float* __restrict__ cout_b,
    const float* __restrict__ sin_w, const float* __restrict__ sin_b,
    const float* __restrict__ sout_w, const float* __restrict__ sout_b,
    const float* __restrict__ oin_w, const float* __restrict__ oin_b,
    const float* __restrict__ oout_w, const float* __restrict__ oout_b,
    const float* __restrict__ fc1_w, const float* __restrict__ fc1_b,
    float* __restrict__ out)
{
  __shared__ __align__(16) float sm[SM_TOTAL];
  const int tid = threadIdx.x;
  const int b = blockIdx.x;

#define CP(off, p, n) for (int i = tid; i < (n); i += NT) sm[(off)+i] = (p)[i]
#define CPQ(off, p, n, nq) for (int i = tid; i < (n); i += NT) sm[(off)+i] = (p)[i] * ((i < (nq)) ? LOG2E : 1.0f)

  // ---------- phase 0: stage weights ----------
  for (int i = tid; i < 640; i += NT) sm[OFF_EEGW + (i / 80) * 84 + (i % 80)] = eeg_w[i];
  CP(OFF_EEGB, eeg_b, 8);
  CP(OFF_PSAW, psa_w, 16);   CP(OFF_PSAB, psa_b, 8);
  CP(OFF_LOCW, loc_w, 24);   CP(OFF_LOCB, loc_b, 8);
  CP(OFF_TGTW, tgt_w, 8);    CP(OFF_TGTB, tgt_b, 8);
  CP(OFF_NG, ng, 8);         CP(OFF_NB, nb, 8);
  CPQ(OFF_CINW, cin_w, 192, 64);  CPQ(OFF_CINB, cin_b, 24, 8);
  CP(OFF_COUTW, cout_w, 64); CP(OFF_COUTB, cout_b, 8);
  CPQ(OFF_SINW, sin_w, 192, 64);  CPQ(OFF_SINB, sin_b, 24, 8);
  CP(OFF_SOUTW, sout_w, 64); CP(OFF_SOUTB, sout_b, 8);
  CPQ(OFF_OINW, oin_w, 192, 64);  CPQ(OFF_OINB, oin_b, 24, 8);
  CP(OFF_OOUTW, oout_w, 64); CP(OFF_OOUTB, oout_b, 8);
  CP(OFF_FC1B, fc1_b, 90);
  if (tid < 16) {
    const float divs[4] = {1.f, 0.1f, 0.01f, 0.001f};
    float pos = (tid < 8) ? 30.f : 32.f;
    int e = tid & 7;
    float x = pos * divs[e >> 1];
    float v = (e & 1) ? cosf(x) : sinf(x);
    sm[((tid < 8) ? OFF_PE30 : OFF_PE32) + e] = v;
  }
  __syncthreads();

  // ---------- phase 1: convs + positional encoding ----------
  if (tid < 240) {  // eeg conv2d -> e[30][8]
    int w = tid >> 3, o = tid & 7;
    const float* ep = eeg + (size_t)b * 4720 + 4 * w;
    const float* wr = sm + OFF_EEGW + o * 84;
    v4f acc4 = {0.f, 0.f, 0.f, 0.f};
    #pragma unroll
    for (int t = 0; t < 20; t++) {
      int ik0 = 2 * t, ik1 = 2 * t + 1;
      float2 x0 = *(const float2*)(ep + (ik0 / 20) * 2360 + (ik0 % 20) * 118);
      float2 x1 = *(const float2*)(ep + (ik1 / 20) * 2360 + (ik1 % 20) * 118);
      v4f xv = {x0.x, x0.y, x1.x, x1.y};
      acc4 += xv * *(const v4f*)(wr + 4 * t);
    }
    sm[OFF_Ebuf + w * 8 + o] = hsum4(acc4) + sm[OFF_EEGB + o] + sm[OFF_PE30 + o];
  }
  {  // conv1d k=1 pad=1 -> length-32 sequences, + pe32
    int t = tid >> 3, o = tid & 7;
    bool inb = (t >= 1 && t <= 30);
    int ti = t - 1;
    float pe = sm[OFF_PE32 + o];
    float w0 = sm[OFF_PSAW + 2 * o], w1 = sm[OFF_PSAW + 2 * o + 1];
    float pb = sm[OFF_PSAB + o];
    float vp = pb, vs = pb, va = pb;
    float vl = sm[OFF_LOCB + o], vt = sm[OFF_TGTB + o];
    if (inb) {
      const float* pp = pupil    + (size_t)b * 60 + ti;
      const float* sp = speech   + (size_t)b * 60 + ti;
      const float* ap = action   + (size_t)b * 60 + ti;
      const float* lp = location + (size_t)b * 90 + ti;
      vp = fmaf(pp[0], w0, fmaf(pp[30], w1, vp));
      vs = fmaf(sp[0], w0, fmaf(sp[30], w1, vs));
      va = fmaf(ap[0], w0, fmaf(ap[30], w1, va));
      vl = fmaf(lp[0],  sm[OFF_LOCW + 3 * o],     vl);
      vl = fmaf(lp[30], sm[OFF_LOCW + 3 * o + 1], vl);
      vl = fmaf(lp[60], sm[OFF_LOCW + 3 * o + 2], vl);
      vt = fmaf(tgt[(size_t)b * 30 + ti], sm[OFF_TGTW + o], vt);
    }
    sm[OFF_Pbuf + tid] = vp + pe;
    sm[OFF_Sbuf + tid] = vs + pe;
    sm[OFF_Abuf + tid] = va + pe;
    sm[OFF_Lbuf + tid] = vl + pe;
    sm[OFF_Tbuf + tid] = vt + pe;
  }
  __syncthreads();

  const int g = tid >> 3, h = tid & 7;
  float* qslot = sm + OFF_QP + g * 20;

  // ---------- phase A: ALL 8 K/V sets, weights hoisted (scoped) ----------
  {
    const int r = g;  // 0..31
    v4f cka = *(const v4f*)(sm + OFF_CINW + 64 + h * 8), ckb = *(const v4f*)(sm + OFF_CINW + 68 + h * 8);
    v4f cva = *(const v4f*)(sm + OFF_CINW + 128 + h * 8), cvb = *(const v4f*)(sm + OFF_CINW + 132 + h * 8);
    float cbk = sm[OFF_CINB + 8 + h], cbv = sm[OFF_CINB + 16 + h];
#define KV1(srcO, set, wka, wkb, wva, wvb, bk, bv) { \
    v4f xa = *(const v4f*)(sm + (srcO) + r * 8); \
    v4f xb = *(const v4f*)(sm + (srcO) + r * 8 + 4); \
    sm[OFF_K8 + (set) * 288 + h * 36 + r] = (bk) + hsum4(xa * (wka) + xb * (wkb)); \
    sm[OFF_V8 + (set) * 288 + h * 36 + r] = (bv) + hsum4(xa * (wva) + xb * (wvb)); }
    if (r < 30) KV1(OFF_Ebuf, 0, cka, ckb, cva, cvb, cbk, cbv);
    KV1(OFF_Pbuf, 1, cka, ckb, cva, cvb, cbk, cbv);
    KV1(OFF_Sbuf, 2, cka, ckb, cva, cvb, cbk, cbv);
    KV1(OFF_Abuf, 3, cka, ckb, cva, cvb, cbk, cbv);
    KV1(OFF_Lbuf, 4, cka, ckb, cva, cvb, cbk, cbv);
    v4f ska = *(const v4f*)(sm + OFF_SINW + 64 + h * 8), skb = *(const v4f*)(sm + OFF_SINW + 68 + h * 8);
    v4f sva = *(const v4f*)(sm + OFF_SINW + 128 + h * 8), svb = *(const v4f*)(sm + OFF_SINW + 132 + h * 8);
    float sbk = sm[OFF_SINB + 8 + h], sbv = sm[OFF_SINB + 16 + h];
    if (r < 30) KV1(OFF_Ebuf, 5, ska, skb, sva, svb, sbk, sbv);
    KV1(OFF_Pbuf, 6, ska, skb, sva, svb, sbk, sbv);
    KV1(OFF_Abuf, 7, ska, skb, sva, svb, sbk, sbv);
#undef KV1
  }
  __syncthreads();

  // ---------- phase B: 18 MHAs, 2 rows/thread, targets split across wave pairs ----------
#define KSET(s) (sm + OFF_K8 + (s) * 288 + h * 36)
#define VSET(s) (sm + OFF_V8 + (s) * 288 + h * 36)
  {
    const float gg = sm[OFF_NG + h], bb = sm[OFF_NB + h];
    float t1, t2;
    if (g < 16) {
      // ---- target e: rows g (0..15) and g+16 (16..29; clamped for g>=14, row2 discarded) ----
      {
        const int r2 = (g < 14) ? (g + 16) : 13;
        float qc1 = dot8(sm + OFF_Ebuf + g * 8,  sm + OFF_CINW + h * 8, sm[OFF_CINB + h]);
        float qc2 = dot8(sm + OFF_Ebuf + r2 * 8, sm + OFF_CINW + h * 8, sm[OFF_CINB + h]);
        float cat1, cat2;
        attn2_nv<32>(qc1, qc2, KSET(1), VSET(1), qslot, h, sm, OFF_COUTW, OFF_COUTB, gg, bb, cat1, cat2); // e,p
        attn2_nv<32>(qc1, qc2, KSET(3), VSET(3), qslot, h, sm, OFF_COUTW, OFF_COUTB, gg, bb, t1, t2);     // e,a
        cat1 += t1; cat2 += t2;
        attn2_nv<32>(qc1, qc2, KSET(4), VSET(4), qslot, h, sm, OFF_COUTW, OFF_COUTB, gg, bb, t1, t2);     // e,l
        cat1 += t1; cat2 += t2;
        float qs1 = dot8(sm + OFF_Ebuf + g * 8,  sm + OFF_SINW + h * 8, sm[OFF_SINB + h]);
        float qs2 = dot8(sm + OFF_Ebuf + r2 * 8, sm + OFF_SINW + h * 8, sm[OFF_SINB + h]);
        attn2_nv<30>(qs1, qs2, KSET(5), VSET(5), qslot, h, sm, OFF_SOUTW, OFF_SOUTB, gg, bb, t1, t2);     // self e
        cat1 += t1; cat2 += t2;
        attn2_nv<32>(qc1, qc2, KSET(2), VSET(2), qslot, h, sm, OFF_COUTW, OFF_COUTB, gg, bb, t1, t2);     // e,s
        cat1 += t1; cat2 += t2;
        sm[OFF_CAT + g * 8 + h] = cat1;
        if (g < 14) sm[OFF_CAT + (g + 16) * 8 + h] = cat2;
      }
      // ---- target p: rows g and g+16 ----
      {
        float qc1 = dot8(sm + OFF_Pbuf + g * 8,        sm + OFF_CINW + h * 8, sm[OFF_CINB + h]);
        float qc2 = dot8(sm + OFF_Pbuf + (g + 16) * 8, sm + OFF_CINW + h * 8, sm[OFF_CINB + h]);
        float cat1, cat2;
        attn2_nv<30>(qc1, qc2, KSET(0), VSET(0), qslot, h, sm, OFF_COUTW, OFF_COUTB, gg, bb, cat1, cat2); // p,e
        attn2_nv<32>(qc1, qc2, KSET(3), VSET(3), qslot, h, sm, OFF_COUTW, OFF_COUTB, gg, bb, t1, t2);     // p,a
        cat1 += t1; cat2 += t2;
        attn2_nv<32>(qc1, qc2, KSET(4), VSET(4), qslot, h, sm, OFF_COUTW, OFF_COUTB, gg, bb, t1, t2);     // p,l
        cat1 += t1; cat2 += t2;
        float qs1 = dot8(sm + OFF_Pbuf + g * 8,        sm + OFF_SINW + h * 8, sm[OFF_SINB + h]);
        float qs2 = dot8(sm + OFF_Pbuf + (g + 16) * 8, sm + OFF_SINW + h * 8, sm[OFF_SINB + h]);
        attn2_nv<32>(qs1, qs2, KSET(6), VSET(6), qslot, h, sm, OFF_SOUTW, OFF_SOUTB, gg, bb, t1, t2);     // self p
        cat1 += t1; cat2 += t2;
        attn2_nv<32>(qc1, qc2, KSET(2), VSET(2), qslot, h, sm, OFF_COUTW, OFF_COUTB, gg, bb, t1, t2);     // p,s
        cat1 += t1; cat2 += t2;
        sm[OFF_CAT + (30 + g) * 8 + h] = cat1;
        sm[OFF_CAT + (30 + g + 16) * 8 + h] = cat2;
      }
    } else {
      const int gq = g - 16;
      float car1, car2;
      // ---- target s: rows gq and gq+16 ----
      {
        float qc1 = dot8(sm + OFF_Sbuf + gq * 8,        sm + OFF_CINW + h * 8, sm[OFF_CINB + h]);
        float qc2 = dot8(sm + OFF_Sbuf + (gq + 16) * 8, sm + OFF_CINW + h * 8, sm[OFF_CINB + h]);
        float cat1, cat2;
        attn2_nv<30>(qc1, qc2, KSET(0), VSET(0), qslot, h, sm, OFF_COUTW, OFF_COUTB, gg, bb, cat1, cat2); // s,e
        attn2_nv<32>(qc1, qc2, KSET(1), VSET(1), qslot, h, sm, OFF_COUTW, OFF_COUTB, gg, bb, t1, t2);     // s,p
        cat1 += t1; cat2 += t2;
        attn2_nv<32>(qc1, qc2, KSET(3), VSET(3), qslot, h, sm, OFF_COUTW, OFF_COUTB, gg, bb, t1, t2);     // s,a
        cat1 += t1; cat2 += t2;
        attn2_nv<32>(qc1, qc2, KSET(4), VSET(4), qslot, h, sm, OFF_COUTW, OFF_COUTB, gg, bb, car1, car2); // s,l
        sm[OFF_CAT + (94 + gq) * 8 + h] = cat1 + car1;
        sm[OFF_CAT + (94 + gq + 16) * 8 + h] = cat2 + car2;
      }
      // ---- target a: rows gq and gq+16 (reuses carry = nrm(cross(s,l)), original bug) ----
      {
        float qc1 = dot8(sm + OFF_Abuf + gq * 8,        sm + OFF_CINW + h * 8, sm[OFF_CINB + h]);
        float qc2 = dot8(sm + OFF_Abuf + (gq + 16) * 8, sm + OFF_CINW + h * 8, sm[OFF_CINB + h]);
        float cat1, cat2;
        attn2_nv<30>(qc1, qc2, KSET(0), VSET(0), qslot, h, sm, OFF_COUTW, OFF_COUTB, gg, bb, cat1, cat2); // a,e
        attn2_nv<32>(qc1, qc2, KSET(1), VSET(1), qslot, h, sm, OFF_COUTW, OFF_COUTB, gg, bb, t1, t2);     // a,p
        cat1 += t1 + car1; cat2 += t2 + car2;
        float qs1 = dot8(sm + OFF_Abuf + gq * 8,        sm + OFF_SINW + h * 8, sm[OFF_SINB + h]);
        float qs2 = dot8(sm + OFF_Abuf + (gq + 16) * 8, sm + OFF_SINW + h * 8, sm[OFF_SINB + h]);
        attn2_nv<32>(qs1, qs2, KSET(7), VSET(7), qslot, h, sm, OFF_SOUTW, OFF_SOUTB, gg, bb, t1, t2);     // self a
        cat1 += t1; cat2 += t2;
        attn2_nv<32>(qc1, qc2, KSET(2), VSET(2), qslot, h, sm, OFF_COUTW, OFF_COUTB, gg, bb, t1, t2);     // a,s
        cat1 += t1; cat2 += t2;
        sm[OFF_CAT + (62 + gq) * 8 + h] = cat1;
        sm[OFF_CAT + (62 + gq + 16) * 8 + h] = cat2;
      }
    }
  }
#undef KSET
#undef VSET
  __syncthreads();

  // ---------- final MHA kv-proj of CAT (126 rows), weights hoisted (scoped) ----------
  {
    v4f fka = *(const v4f*)(sm + OFF_OINW + 64 + h * 8), fkb = *(const v4f*)(sm + OFF_OINW + 68 + h * 8);
    v4f fva = *(const v4f*)(sm + OFF_OINW + 128 + h * 8), fvb = *(const v4f*)(sm + OFF_OINW + 132 + h * 8);
    float fbk = sm[OFF_OINB + 8 + h], fbv = sm[OFF_OINB + 16 + h];
    for (int r = g; r < 126; r += 32) {
      v4f xa = *(const v4f*)(sm + OFF_CAT + r * 8);
      v4f xb = *(const v4f*)(sm + OFF_CAT + r * 8 + 4);
      sm[OFF_KF + h * 132 + r] = fbk + hsum4(xa * fka + xb * fkb);
      sm[OFF_VF + h * 132 + r] = fbv + hsum4(xa * fva + xb * fvb);
    }
  }
  __syncthreads();

  // ---------- final attention (Lk=126, 2 rows/thread, waves 2-3) ----------
  if (g >= 16) {
    const int gq = g - 16;
    float qf1 = dot8(sm + OFF_Tbuf + gq * 8,        sm + OFF_OINW + h * 8, sm[OFF_OINB + h]);
    float qf2 = dot8(sm + OFF_Tbuf + (gq + 16) * 8, sm + OFF_OINW + h * 8, sm[OFF_OINB + h]);
    float ov1, ov2;
    attn2_core<126>(qf1, qf2, sm + OFF_KF + h * 132, sm + OFF_VF + h * 132, ov1, ov2);
    qslot[h] = ov1; qslot[8 + h] = ov2;
    float a1 = dot8(qslot,     sm + OFF_OOUTW + h * 8, sm[OFF_OOUTB + h]);
    float a2 = dot8(qslot + 8, sm + OFF_OOUTW + h * 8, sm[OFF_OOUTB + h]);
    sm[OFF_Tbuf + gq * 8 + h]        = a1;
    sm[OFF_Tbuf + (gq + 16) * 8 + h] = a2;
  }
  __syncthreads();

  // ---------- fc1 (2 threads per output) + channel softmax ----------
  if (tid < 180) {
    int j = tid >> 1, p = tid & 1;
    const v4f* w4 = (const v4f*)(fc1_w + j * 256);
    const v4f* o4 = (const v4f*)(sm + OFF_Tbuf);
    v4f acc4 = {0.f, 0.f, 0.f, 0.f};
    #pragma unroll 8
    for (int c = p; c < 64; c += 2) acc4 += o4[c] * w4[c];
    float acc = hsum4(acc4);
    acc += __shfl_xor(acc, 1);
    if (p == 0) sm[OFF_FCO + j] = acc + sm[OFF_FC1B + j];
  }
  __syncthreads();
  if (tid < 30) {
    float x0 = sm[OFF_FCO + 3 * tid], x1 = sm[OFF_FCO + 3 * tid + 1], x2 = sm[OFF_FCO + 3 * tid + 2];
    float m = fmaxf(x0, fmaxf(x1, x2));
    float e0 = __expf(x0 - m), e1 = __expf(x1 - m), e2 = __expf(x2 - m);
    float inv = __builtin_amdgcn_rcpf(e0 + e1 + e2);
    float* op = out + (size_t)b * 90;
    op[tid]      = e0 * inv;
    op[30 + tid] = e1 * inv;
    op[60 + tid] = e2 * inv;
  }
#undef CP
#undef CPQ
}

extern "C" void kernel_launch(void* const* d_in, const int* in_sizes, int n_in,
                              void* d_out, int out_size, void* d_ws, size_t ws_size,
                              hipStream_t stream) {
  (void)n_in; (void)out_size; (void)d_ws; (void)ws_size;
  int B = in_sizes[0] / 4720;  // eeg = (B,2,20,118)
  cmt_kernel<<<B, NT, 0, stream>>>(
      (const float*)d_in[0],  (const float*)d_in[1],  (const float*)d_in[2],
      (const float*)d_in[3],  (const float*)d_in[4],  (const float*)d_in[5],
      (const float*)d_in[6],  (const float*)d_in[7],  (const float*)d_in[8],
      (const float*)d_in[9],  (const float*)d_in[10], (const float*)d_in[11],
      (const float*)d_in[12], (const float*)d_in[13], (const float*)d_in[14],
      (const float*)d_in[15], (const float*)d_in[16], (const float*)d_in[17],
      (const float*)d_in[18], (const float*)d_in[19], (const float*)d_in[20],
      (const float*)d_in[21], (const float*)d_in[22], (const float*)d_in[23],
      (const float*)d_in[24], (const float*)d_in[25], (const float*)d_in[26],
      (const float*)d_in[27], (const float*)d_in[28], (const float*)d_in[29],
      (float*)d_out);
}